// Round 2
// baseline (408.222 us; speedup 1.0000x reference)
//
#include <hip/hip_runtime.h>
#include <math.h>

#define NN 8192
#define DD 512

// ---------------- CSR build ----------------
__global__ __launch_bounds__(256) void deg_kernel(const int* __restrict__ ei,
                                                  int* __restrict__ deg, int E) {
    int e = blockIdx.x * 256 + threadIdx.x;
    if (e < E) atomicAdd(&deg[ei[E + e]], 1);
}

__global__ __launch_bounds__(1024) void scan_kernel(const int* __restrict__ deg,
                                                    int* __restrict__ row_ptr) {
    __shared__ int sums[1024];
    int tid = threadIdx.x;
    int base = tid * 8;
    int local[8];
    int s = 0;
#pragma unroll
    for (int i = 0; i < 8; i++) { local[i] = s; s += deg[base + i]; }
    sums[tid] = s;
    __syncthreads();
    for (int off = 1; off < 1024; off <<= 1) {
        int v = sums[tid];
        int u = (tid >= off) ? sums[tid - off] : 0;
        __syncthreads();
        sums[tid] = v + u;
        __syncthreads();
    }
    int prev = (tid == 0) ? 0 : sums[tid - 1];
#pragma unroll
    for (int i = 0; i < 8; i++) row_ptr[base + i] = prev + local[i];
    if (tid == 1023) row_ptr[NN] = sums[1023];
}

__global__ __launch_bounds__(256) void scatter_kernel(const int* __restrict__ ei,
                                                      const int* __restrict__ row_ptr,
                                                      int* __restrict__ cursor,
                                                      int* __restrict__ csr, int E) {
    int e = blockIdx.x * 256 + threadIdx.x;
    if (e < E) {
        int dst = ei[E + e];
        int src = ei[e];
        int pos = row_ptr[dst] + atomicAdd(&cursor[dst], 1);
        csr[pos] = src;
    }
}

// ---------------- mean aggregation ----------------
// one block per dst node, 128 threads x float4 = 512 features
__global__ __launch_bounds__(128) void agg_kernel(const float* __restrict__ x,
                                                  const int* __restrict__ row_ptr,
                                                  const int* __restrict__ csr,
                                                  float* __restrict__ agg) {
    int dst = blockIdx.x;
    int tid = threadIdx.x;
    int s = row_ptr[dst], e = row_ptr[dst + 1];
    float4 acc = make_float4(0.f, 0.f, 0.f, 0.f);
    const float4* x4 = (const float4*)x;
    for (int p = s; p < e; p++) {
        int src = csr[p];
        float4 v = x4[(size_t)src * 128 + tid];
        acc.x += v.x; acc.y += v.y; acc.z += v.z; acc.w += v.w;
    }
    float inv = 1.0f / fmaxf((float)(e - s), 1.0f);
    acc.x *= inv; acc.y *= inv; acc.z *= inv; acc.w *= inv;
    ((float4*)agg)[(size_t)dst * 128 + tid] = acc;
}

// ---------------- f32 GEMM, 128x128 tile, 8x8 micro, optional dual-A fused ----------------
// C = act(A1@B1 [+ A2@B2] + bias), all row-major, M%128==0, N%128==0, K%16==0
__global__ __launch_bounds__(256) void gemm128(const float* __restrict__ A1,
                                               const float* __restrict__ B1,
                                               const float* __restrict__ A2,
                                               const float* __restrict__ B2,
                                               const float* __restrict__ bias,
                                               float* __restrict__ C,
                                               int M, int N, int K, int relu) {
    __shared__ float As[16][132];
    __shared__ float Bs[16][132];
    const int tid = threadIdx.x;
    const int tx = tid & 15, ty = tid >> 4;
    const int row0 = blockIdx.y * 128;
    const int col0 = blockIdx.x * 128;
    float acc[2][2][4][4] = {};
    const int npass = (A2 != nullptr) ? 2 : 1;
    for (int pass = 0; pass < npass; ++pass) {
        const float* __restrict__ A = pass ? A2 : A1;
        const float* __restrict__ B = pass ? B2 : B1;
        for (int k0 = 0; k0 < K; k0 += 16) {
            {   // A tile: 128 rows x 16 k, stored transposed As[k][row]
                int r = tid >> 1;
                int kk = (tid & 1) * 8;
                const float* ap = A + (size_t)(row0 + r) * K + k0 + kk;
                float4 a0 = *(const float4*)ap;
                float4 a1 = *(const float4*)(ap + 4);
                As[kk + 0][r] = a0.x; As[kk + 1][r] = a0.y;
                As[kk + 2][r] = a0.z; As[kk + 3][r] = a0.w;
                As[kk + 4][r] = a1.x; As[kk + 5][r] = a1.y;
                As[kk + 6][r] = a1.z; As[kk + 7][r] = a1.w;
            }
            {   // B tile: 16 k x 128 cols
                int kk = tid >> 4;
                int c = (tid & 15) * 8;
                const float* bp = B + (size_t)(k0 + kk) * N + col0 + c;
                *(float4*)&Bs[kk][c]     = *(const float4*)bp;
                *(float4*)&Bs[kk][c + 4] = *(const float4*)(bp + 4);
            }
            __syncthreads();
#pragma unroll
            for (int k = 0; k < 16; k++) {
                float4 a0 = *(const float4*)&As[k][ty * 4];
                float4 a1 = *(const float4*)&As[k][ty * 4 + 64];
                float4 b0 = *(const float4*)&Bs[k][tx * 4];
                float4 b1 = *(const float4*)&Bs[k][tx * 4 + 64];
                float av[8] = {a0.x, a0.y, a0.z, a0.w, a1.x, a1.y, a1.z, a1.w};
                float bv[8] = {b0.x, b0.y, b0.z, b0.w, b1.x, b1.y, b1.z, b1.w};
#pragma unroll
                for (int qi = 0; qi < 2; qi++)
#pragma unroll
                    for (int i = 0; i < 4; i++)
#pragma unroll
                        for (int qj = 0; qj < 2; qj++)
#pragma unroll
                            for (int j = 0; j < 4; j++)
                                acc[qi][qj][i][j] += av[qi * 4 + i] * bv[qj * 4 + j];
            }
            __syncthreads();
        }
    }
#pragma unroll
    for (int qi = 0; qi < 2; qi++)
#pragma unroll
        for (int qj = 0; qj < 2; qj++)
#pragma unroll
            for (int i = 0; i < 4; i++) {
                int r = row0 + qi * 64 + ty * 4 + i;
                int cb = col0 + qj * 64 + tx * 4;
                float4 o;
                float* op = (float*)&o;
#pragma unroll
                for (int j = 0; j < 4; j++) {
                    float v = acc[qi][qj][i][j] + bias[cb + j];
                    op[j] = relu ? fmaxf(v, 0.f) : v;
                }
                *(float4*)(C + (size_t)r * N + cb) = o;
            }
}

// ---------------- f32 GEMM, 64x64 tile, 4x4 micro (tail layers) ----------------
__global__ __launch_bounds__(256) void gemm64(const float* __restrict__ A,
                                              const float* __restrict__ B,
                                              const float* __restrict__ bias,
                                              float* __restrict__ C,
                                              int M, int N, int K, int relu) {
    __shared__ float As[16][68];
    __shared__ float Bs[16][68];
    const int tid = threadIdx.x;
    const int tx = tid & 15, ty = tid >> 4;
    const int row0 = blockIdx.y * 64;
    const int col0 = blockIdx.x * 64;
    float acc[4][4] = {};
    for (int k0 = 0; k0 < K; k0 += 16) {
        {
            int r = tid >> 2;
            int kk = (tid & 3) * 4;
            float4 a = *(const float4*)(A + (size_t)(row0 + r) * K + k0 + kk);
            As[kk + 0][r] = a.x; As[kk + 1][r] = a.y;
            As[kk + 2][r] = a.z; As[kk + 3][r] = a.w;
        }
        {
            int kk = tid >> 4;
            int c = (tid & 15) * 4;
            *(float4*)&Bs[kk][c] = *(const float4*)(B + (size_t)(k0 + kk) * N + col0 + c);
        }
        __syncthreads();
#pragma unroll
        for (int k = 0; k < 16; k++) {
            float4 a = *(const float4*)&As[k][ty * 4];
            float4 b = *(const float4*)&Bs[k][tx * 4];
            float av[4] = {a.x, a.y, a.z, a.w};
            float bv[4] = {b.x, b.y, b.z, b.w};
#pragma unroll
            for (int i = 0; i < 4; i++)
#pragma unroll
                for (int j = 0; j < 4; j++)
                    acc[i][j] += av[i] * bv[j];
        }
        __syncthreads();
    }
#pragma unroll
    for (int i = 0; i < 4; i++) {
        int r = row0 + ty * 4 + i;
        int cb = col0 + tx * 4;
        float4 o;
        float* op = (float*)&o;
#pragma unroll
        for (int j = 0; j < 4; j++) {
            float v = acc[i][j] + bias[cb + j];
            op[j] = relu ? fmaxf(v, 0.f) : v;
        }
        *(float4*)(C + (size_t)r * N + cb) = o;
    }
}

// ---------------- final tiny layer: y[row] = h4[row]@W3 + b3 (pad to float4) ----------------
__global__ __launch_bounds__(256) void out3_kernel(const float* __restrict__ h4,
                                                   const float* __restrict__ W3,
                                                   const float* __restrict__ b3,
                                                   float* __restrict__ y) {
    int row = blockIdx.x * 256 + threadIdx.x;
    float a0 = b3[0], a1 = b3[1], a2 = b3[2];
    const float* hr = h4 + (size_t)row * 64;
#pragma unroll
    for (int k = 0; k < 64; k++) {
        float v = hr[k];
        a0 += v * W3[k * 3 + 0];
        a1 += v * W3[k * 3 + 1];
        a2 += v * W3[k * 3 + 2];
    }
    float4 o = make_float4(a0, a1, a2, 0.f);
    ((float4*)y)[row] = o;
}

// ---------------- cdist: block = 64 rows x 256 cols, thread = 16 rows x 4 cols ----------------
__global__ __launch_bounds__(256) void cdist_kernel(const float* __restrict__ y4,
                                                    float* __restrict__ out) {
    int tx = threadIdx.x & 63;
    int ty = threadIdx.x >> 6;
    int j0 = blockIdx.x * 256 + tx * 4;
    int i0 = blockIdx.y * 64 + ty * 16;
    float jx[4], jy[4], jz[4];
    const float4* yv = (const float4*)y4;
#pragma unroll
    for (int j = 0; j < 4; j++) {
        float4 t = yv[j0 + j];
        jx[j] = t.x; jy[j] = t.y; jz[j] = t.z;
    }
#pragma unroll
    for (int i = 0; i < 16; i++) {
        float4 ti = yv[i0 + i];
        float4 o;
        float* op = (float*)&o;
#pragma unroll
        for (int j = 0; j < 4; j++) {
            float dx = ti.x - jx[j];
            float dy = ti.y - jy[j];
            float dz = ti.z - jz[j];
            op[j] = sqrtf(dx * dx + dy * dy + dz * dz);
        }
        *(float4*)(out + (size_t)(i0 + i) * NN + j0) = o;
    }
}

extern "C" void kernel_launch(void* const* d_in, const int* in_sizes, int n_in,
                              void* d_out, int out_size, void* d_ws, size_t ws_size,
                              hipStream_t stream) {
    const float* x   = (const float*)d_in[0];
    const int*   ei  = (const int*)d_in[1];   // harness passes integer inputs as int32
    const float* W_l = (const float*)d_in[2];
    const float* b_l = (const float*)d_in[3];
    const float* W_r = (const float*)d_in[4];
    const float* Wa  = (const float*)d_in[5];
    const float* ba  = (const float*)d_in[6];
    const float* W1  = (const float*)d_in[7];
    const float* b1  = (const float*)d_in[8];
    const float* W2  = (const float*)d_in[9];
    const float* b2  = (const float*)d_in[10];
    const float* W3  = (const float*)d_in[11];
    const float* b3  = (const float*)d_in[12];
    float* out = (float*)d_out;
    const int E = in_sizes[1] / 2;

    // ---- workspace carving ----
    // Total scratch need:
    const size_t need = ((size_t)NN * 4 + 255 & ~(size_t)255)          // deg
                      + (((size_t)(NN + 1) * 4 + 255) & ~(size_t)255)  // row_ptr
                      + ((size_t)NN * 4 + 255 & ~(size_t)255)          // cursor
                      + (((size_t)E * 4 + 255) & ~(size_t)255)         // csr
                      + ((size_t)NN * 16 + 255 & ~(size_t)255)         // yv
                      + (size_t)NN * 512 * 4                           // agg
                      + (size_t)NN * 512 * 4                           // h1
                      + (size_t)NN * 256 * 4                           // h2
                      + (size_t)NN * 128 * 4                           // h3
                      + (size_t)NN * 64 * 4                            // h4
                      + 8192;
    // If d_ws is too small, carve everything from d_out (256 MB; cdist writes it
    // last and reads only yv, which we then place in d_out's tail region too —
    // all intermediates are dead by the time cdist runs).
    char* base = ((size_t)ws_size >= need) ? (char*)d_ws : (char*)d_out;
    size_t off = 0;
    auto carve = [&](size_t bytes) -> char* {
        char* p = base + off;
        off += (bytes + 255) & ~(size_t)255;
        return p;
    };
    int*   deg     = (int*)carve(NN * 4);
    int*   row_ptr = (int*)carve((NN + 1) * 4);
    int*   cursor  = (int*)carve(NN * 4);
    int*   csr     = (int*)carve((size_t)E * 4);
    float* yv      = (float*)carve((size_t)NN * 4 * 4);
    float* agg     = (float*)carve((size_t)NN * 512 * 4);
    float* h1      = (float*)carve((size_t)NN * 512 * 4);
    float* h2      = (float*)carve((size_t)NN * 256 * 4);
    float* h3      = (float*)carve((size_t)NN * 128 * 4);
    float* h4      = (float*)carve((size_t)NN * 64 * 4);

    // ---- CSR build ----
    hipMemsetAsync(deg, 0, NN * 4, stream);
    hipMemsetAsync(cursor, 0, NN * 4, stream);
    deg_kernel<<<(E + 255) / 256, 256, 0, stream>>>(ei, deg, E);
    scan_kernel<<<1, 1024, 0, stream>>>(deg, row_ptr);
    scatter_kernel<<<(E + 255) / 256, 256, 0, stream>>>(ei, row_ptr, cursor, csr, E);

    // ---- aggregation ----
    agg_kernel<<<NN, 128, 0, stream>>>(x, row_ptr, csr, agg);

    // ---- MLP chain ----
    // h1 = relu(agg@W_l + x@W_r + b_l)   [8192,512]
    gemm128<<<dim3(512 / 128, NN / 128), 256, 0, stream>>>(agg, W_l, x, W_r, b_l, h1,
                                                           NN, 512, 512, 1);
    // h2 = relu(h1@Wa + ba)              [8192,256]
    gemm128<<<dim3(256 / 128, NN / 128), 256, 0, stream>>>(h1, Wa, nullptr, nullptr, ba, h2,
                                                           NN, 256, 512, 1);
    // h3 = relu(h2@W1 + b1)              [8192,128]
    gemm64<<<dim3(128 / 64, NN / 64), 256, 0, stream>>>(h2, W1, b1, h3, NN, 128, 256, 1);
    // h4 = relu(h3@W2 + b2)              [8192,64]
    gemm64<<<dim3(64 / 64, NN / 64), 256, 0, stream>>>(h3, W2, b2, h4, NN, 64, 128, 1);
    // y = h4@W3 + b3                      [8192,3] (padded float4)
    out3_kernel<<<NN / 256, 256, 0, stream>>>(h4, W3, b3, yv);

    // ---- cdist ----
    cdist_kernel<<<dim3(NN / 256, NN / 64), 256, 0, stream>>>(yv, out);
}

// Round 3
// 221.587 us; speedup vs baseline: 1.8423x; 1.8423x over previous
//
#include <hip/hip_runtime.h>
#include <math.h>

#define NN 8192
#define DD 512

typedef _Float16 f16;
typedef _Float16 half8 __attribute__((ext_vector_type(8)));
typedef _Float16 half4 __attribute__((ext_vector_type(4)));
typedef float f32x4 __attribute__((ext_vector_type(4)));

typedef const __attribute__((address_space(1))) unsigned int* gptr_t;
typedef __attribute__((address_space(3))) unsigned int* lptr_t;

__device__ __forceinline__ void gload16(const void* g, void* l) {
    // async global->LDS, 16B per lane, LDS dest = uniform base + lane*16
    __builtin_amdgcn_global_load_lds((gptr_t)g, (lptr_t)l, 16, 0, 0);
}

// ---------------- CSR build ----------------
__global__ __launch_bounds__(256) void deg_kernel(const int* __restrict__ ei,
                                                  int* __restrict__ deg, int E) {
    int e = blockIdx.x * 256 + threadIdx.x;
    if (e < E) atomicAdd(&deg[ei[E + e]], 1);
}

__global__ __launch_bounds__(1024) void scan_kernel(const int* __restrict__ deg,
                                                    int* __restrict__ row_ptr) {
    __shared__ int sums[1024];
    int tid = threadIdx.x;
    int base = tid * 8;
    int local[8];
    int s = 0;
#pragma unroll
    for (int i = 0; i < 8; i++) { local[i] = s; s += deg[base + i]; }
    sums[tid] = s;
    __syncthreads();
    for (int off = 1; off < 1024; off <<= 1) {
        int v = sums[tid];
        int u = (tid >= off) ? sums[tid - off] : 0;
        __syncthreads();
        sums[tid] = v + u;
        __syncthreads();
    }
    int prev = (tid == 0) ? 0 : sums[tid - 1];
#pragma unroll
    for (int i = 0; i < 8; i++) row_ptr[base + i] = prev + local[i];
    if (tid == 1023) row_ptr[NN] = sums[1023];
}

__global__ __launch_bounds__(256) void scatter_kernel(const int* __restrict__ ei,
                                                      const int* __restrict__ row_ptr,
                                                      int* __restrict__ cursor,
                                                      int* __restrict__ csr, int E) {
    int e = blockIdx.x * 256 + threadIdx.x;
    if (e < E) {
        int dst = ei[E + e];
        int src = ei[e];
        int pos = row_ptr[dst] + atomicAdd(&cursor[dst], 1);
        csr[pos] = src;
    }
}

// ---------------- mean aggregation: one wave per node, f16 output ----------------
__global__ __launch_bounds__(256) void agg_kernel(const float* __restrict__ x,
                                                  const int* __restrict__ row_ptr,
                                                  const int* __restrict__ csr,
                                                  f16* __restrict__ aggh) {
    int node = blockIdx.x * 4 + (threadIdx.x >> 6);
    int l = threadIdx.x & 63;
    int s = row_ptr[node], e = row_ptr[node + 1];
    const float4* xb = (const float4*)x;
    float ax0=0,ay0=0,az0=0,aw0=0, ax1=0,ay1=0,az1=0,aw1=0;
    for (int p = s; p < e; p++) {
        int src = csr[p];
        const float4* r = xb + (size_t)src * 128 + l * 2;
        float4 v0 = r[0];
        float4 v1 = r[1];
        ax0 += v0.x; ay0 += v0.y; az0 += v0.z; aw0 += v0.w;
        ax1 += v1.x; ay1 += v1.y; az1 += v1.z; aw1 += v1.w;
    }
    float inv = 1.0f / fmaxf((float)(e - s), 1.0f);
    half8 h;
    h[0] = (f16)(ax0 * inv); h[1] = (f16)(ay0 * inv);
    h[2] = (f16)(az0 * inv); h[3] = (f16)(aw0 * inv);
    h[4] = (f16)(ax1 * inv); h[5] = (f16)(ay1 * inv);
    h[6] = (f16)(az1 * inv); h[7] = (f16)(aw1 * inv);
    ((half8*)aggh)[(size_t)node * 64 + l] = h;
}

// ---------------- f32 -> f16 elementwise (x) ----------------
__global__ __launch_bounds__(256) void cvt_f16_kernel(const float* __restrict__ in,
                                                      f16* __restrict__ out) {
    int i = blockIdx.x * 256 + threadIdx.x;   // group of 8 elements
    const float4* p = (const float4*)in + (size_t)i * 2;
    float4 v0 = p[0], v1 = p[1];
    half8 h;
    h[0] = (f16)v0.x; h[1] = (f16)v0.y; h[2] = (f16)v0.z; h[3] = (f16)v0.w;
    h[4] = (f16)v1.x; h[5] = (f16)v1.y; h[6] = (f16)v1.z; h[7] = (f16)v1.w;
    ((half8*)out)[i] = h;
}

// ---------------- W[K,N] f32 -> Wt[N,K] f16 ----------------
__global__ __launch_bounds__(256) void transpose_f16(const float* __restrict__ W,
                                                     f16* __restrict__ Wt,
                                                     int Kw, int Nw) {
    __shared__ float tile[32][33];
    int n0 = blockIdx.x * 32, k0 = blockIdx.y * 32;
    int t = threadIdx.x;
    {
        int r = t >> 3, cq = (t & 7) * 4;
        float4 v = *(const float4*)(W + (size_t)(k0 + r) * Nw + n0 + cq);
        tile[r][cq] = v.x; tile[r][cq + 1] = v.y; tile[r][cq + 2] = v.z; tile[r][cq + 3] = v.w;
    }
    __syncthreads();
    {
        int n = t >> 3, rq = (t & 7) * 4;
        half4 h;
        h[0] = (f16)tile[rq][n]; h[1] = (f16)tile[rq + 1][n];
        h[2] = (f16)tile[rq + 2][n]; h[3] = (f16)tile[rq + 3][n];
        *(half4*)(Wt + (size_t)(n0 + n) * Kw + k0 + rq) = h;
    }
}

// ---------------- MFMA f16 GEMM: C = relu(A1@B1t^T [+ A2@B2t^T] + bias) ----------------
// A [M,K] f16 row-major; Bt [N,K] f16 row-major (pre-transposed weights).
// Tile BM x BN, K-step 32, wave grid WM x WN. LDS tiles [row][32k], 64B rows,
// XOR-swizzled 16B slots: stored slot s' holds data slot s' ^ ((row>>1)&3).
template<int BM, int BN, int WM, int WN, int NT>
__global__ __launch_bounds__(NT) void gemm_mfma(const f16* __restrict__ A1,
                                                const f16* __restrict__ B1,
                                                const f16* __restrict__ A2,
                                                const f16* __restrict__ B2,
                                                const float* __restrict__ bias,
                                                f16* __restrict__ C,
                                                int M, int N, int K, int relu) {
    constexpr int NWAVES = WM * WN;
    constexpr int FM = BM / (WM * 16);
    constexpr int FN = BN / (WN * 16);
    constexpr int ACH = BM / 16;
    constexpr int NCH = (BM + BN) / 16;
    __shared__ f16 As[2][BM * 32];
    __shared__ f16 Bs[2][BN * 32];

    const int tid = threadIdx.x;
    const int l = tid & 63;
    const int wid = tid >> 6;
    const int wr = wid / WN, wc = wid % WN;
    const int row0 = blockIdx.y * BM;
    const int col0 = blockIdx.x * BN;
    const int rowc = l >> 2;   // row within 16-row chunk
    const int sp = l & 3;      // stored 16B slot

    f32x4 acc[FM][FN];
#pragma unroll
    for (int i = 0; i < FM; i++)
#pragma unroll
        for (int j = 0; j < FN; j++)
#pragma unroll
            for (int q = 0; q < 4; q++) acc[i][j][q] = 0.0f;

    const int ktiles = K >> 5;
    const int npass = (A2 != nullptr) ? 2 : 1;
    const int nt = ktiles * npass;

    auto stage = [&](int buf, int t) {
        int pass = (t >= ktiles) ? 1 : 0;
        int kk = (t - pass * ktiles) << 5;
        const f16* Ag = pass ? A2 : A1;
        const f16* Bg = pass ? B2 : B1;
#pragma unroll
        for (int c = wid; c < NCH; c += NWAVES) {
            bool isA = (c < ACH);
            int cc = isA ? c : c - ACH;
            int row = cc * 16 + rowc;
            int slot = sp ^ ((row >> 1) & 3);
            const f16* g;
            f16* ld;
            if (isA) {
                g = Ag + (size_t)(row0 + row) * K + kk + slot * 8;
                ld = &As[buf][cc * 512];
            } else {
                g = Bg + (size_t)(col0 + row) * K + kk + slot * 8;
                ld = &Bs[buf][cc * 512];
            }
            gload16(g, ld);
        }
    };

    stage(0, 0);
    __syncthreads();
    for (int t = 0; t < nt; ++t) {
        int cur = t & 1;
        if (t + 1 < nt) stage(cur ^ 1, t + 1);
        half8 af[FM], bf[FN];
#pragma unroll
        for (int i = 0; i < FM; i++) {
            int r = wr * FM * 16 + i * 16 + (l & 15);
            int off = r * 64 + ((((l >> 4) ^ ((r >> 1) & 3))) << 4);
            af[i] = *(const half8*)((const char*)As[cur] + off);
        }
#pragma unroll
        for (int j = 0; j < FN; j++) {
            int r = wc * FN * 16 + j * 16 + (l & 15);
            int off = r * 64 + ((((l >> 4) ^ ((r >> 1) & 3))) << 4);
            bf[j] = *(const half8*)((const char*)Bs[cur] + off);
        }
#pragma unroll
        for (int i = 0; i < FM; i++)
#pragma unroll
            for (int j = 0; j < FN; j++)
                acc[i][j] = __builtin_amdgcn_mfma_f32_16x16x32_f16(af[i], bf[j], acc[i][j], 0, 0, 0);
        __syncthreads();
    }

    // epilogue: C/D layout col=lane&15, row=(lane>>4)*4+reg  [m89-verified]
#pragma unroll
    for (int i = 0; i < FM; i++)
#pragma unroll
        for (int j = 0; j < FN; j++) {
            int row = row0 + wr * FM * 16 + i * 16 + ((l >> 4) << 2);
            int col = col0 + wc * FN * 16 + j * 16 + (l & 15);
            float bv = bias[col];
#pragma unroll
            for (int q = 0; q < 4; q++) {
                float v = acc[i][j][q] + bv;
                if (relu) v = fmaxf(v, 0.0f);
                C[(size_t)(row + q) * N + col] = (f16)v;
            }
        }
}

// ---------------- final tiny layer: y[row] = h4[row]@W3 + b3 (f16 in, f32 out) ----------------
__global__ __launch_bounds__(256) void out3_kernel(const f16* __restrict__ h4,
                                                   const float* __restrict__ W3,
                                                   const float* __restrict__ b3,
                                                   float* __restrict__ y) {
    int row = blockIdx.x * 256 + threadIdx.x;
    const half8* hr = (const half8*)(h4 + (size_t)row * 64);
    float a0 = b3[0], a1 = b3[1], a2 = b3[2];
#pragma unroll
    for (int g = 0; g < 8; g++) {
        half8 hv = hr[g];
#pragma unroll
        for (int j = 0; j < 8; j++) {
            float v = (float)hv[j];
            int k = g * 8 + j;
            a0 += v * W3[k * 3 + 0];
            a1 += v * W3[k * 3 + 1];
            a2 += v * W3[k * 3 + 2];
        }
    }
    ((float4*)y)[row] = make_float4(a0, a1, a2, 0.0f);
}

// ---------------- cdist: block = 64 rows x 256 cols, thread = 16 rows x 4 cols ----------------
__global__ __launch_bounds__(256) void cdist_kernel(const float* __restrict__ y4,
                                                    float* __restrict__ out) {
    int tx = threadIdx.x & 63;
    int ty = threadIdx.x >> 6;
    int j0 = blockIdx.x * 256 + tx * 4;
    int i0 = blockIdx.y * 64 + ty * 16;
    float jx[4], jy[4], jz[4];
    const float4* yv = (const float4*)y4;
#pragma unroll
    for (int j = 0; j < 4; j++) {
        float4 t = yv[j0 + j];
        jx[j] = t.x; jy[j] = t.y; jz[j] = t.z;
    }
#pragma unroll
    for (int i = 0; i < 16; i++) {
        float4 ti = yv[i0 + i];
        float4 o;
        float* op = (float*)&o;
#pragma unroll
        for (int j = 0; j < 4; j++) {
            float dx = ti.x - jx[j];
            float dy = ti.y - jy[j];
            float dz = ti.z - jz[j];
            op[j] = sqrtf(dx * dx + dy * dy + dz * dz);
        }
        *(float4*)(out + (size_t)(i0 + i) * NN + j0) = o;
    }
}

extern "C" void kernel_launch(void* const* d_in, const int* in_sizes, int n_in,
                              void* d_out, int out_size, void* d_ws, size_t ws_size,
                              hipStream_t stream) {
    const float* x   = (const float*)d_in[0];
    const int*   ei  = (const int*)d_in[1];
    const float* W_l = (const float*)d_in[2];
    const float* b_l = (const float*)d_in[3];
    const float* W_r = (const float*)d_in[4];
    const float* Wa  = (const float*)d_in[5];
    const float* ba  = (const float*)d_in[6];
    const float* W1  = (const float*)d_in[7];
    const float* b1  = (const float*)d_in[8];
    const float* W2  = (const float*)d_in[9];
    const float* b2  = (const float*)d_in[10];
    const float* W3  = (const float*)d_in[11];
    const float* b3  = (const float*)d_in[12];
    float* out = (float*)d_out;
    const int E = in_sizes[1] / 2;

    auto al = [](size_t b) { return (b + 255) & ~(size_t)255; };
    const size_t small_need = al(NN * 4) + al((NN + 1) * 4) + al(NN * 4) +
                              al((size_t)E * 4) + al((size_t)NN * 16) +
                              al(512 * 512 * 2) * 2 + al(512 * 256 * 2) +
                              al(256 * 128 * 2) + al(128 * 64 * 2);
    const size_t act_need = al((size_t)NN * 512 * 2) * 2 + al((size_t)NN * 512 * 2) +
                            al((size_t)NN * 256 * 2) + al((size_t)NN * 128 * 2) +
                            al((size_t)NN * 64 * 2);
    char* sbase;
    char* abase;
    if (ws_size >= small_need + act_need) {
        sbase = (char*)d_ws; abase = (char*)d_ws + small_need;
    } else if (ws_size >= small_need) {
        sbase = (char*)d_ws; abase = (char*)d_out;   // activations dead before cdist writes
    } else {
        sbase = (char*)d_out; abase = (char*)d_out + small_need;  // last resort
    }
    size_t so = 0, ao = 0;
    auto carve_s = [&](size_t b) { char* p = sbase + so; so += al(b); return p; };
    auto carve_a = [&](size_t b) { char* p = abase + ao; ao += al(b); return p; };

    int*   deg     = (int*)carve_s(NN * 4);
    int*   row_ptr = (int*)carve_s((NN + 1) * 4);
    int*   cursor  = (int*)carve_s(NN * 4);
    int*   csr     = (int*)carve_s((size_t)E * 4);
    float* yv      = (float*)carve_s((size_t)NN * 16);
    f16*   Wlt     = (f16*)carve_s(512 * 512 * 2);
    f16*   Wrt     = (f16*)carve_s(512 * 512 * 2);
    f16*   Wat     = (f16*)carve_s(512 * 256 * 2);
    f16*   W1t     = (f16*)carve_s(256 * 128 * 2);
    f16*   W2t     = (f16*)carve_s(128 * 64 * 2);

    f16* x_h   = (f16*)carve_a((size_t)NN * 512 * 2);
    f16* agg_h = (f16*)carve_a((size_t)NN * 512 * 2);
    f16* h1    = (f16*)carve_a((size_t)NN * 512 * 2);
    f16* h2    = (f16*)carve_a((size_t)NN * 256 * 2);
    f16* h3    = (f16*)carve_a((size_t)NN * 128 * 2);
    f16* h4    = (f16*)carve_a((size_t)NN * 64 * 2);

    // ---- CSR build ----
    hipMemsetAsync(deg, 0, NN * 4, stream);
    hipMemsetAsync(cursor, 0, NN * 4, stream);
    deg_kernel<<<(E + 255) / 256, 256, 0, stream>>>(ei, deg, E);
    scan_kernel<<<1, 1024, 0, stream>>>(deg, row_ptr);
    scatter_kernel<<<(E + 255) / 256, 256, 0, stream>>>(ei, row_ptr, cursor, csr, E);

    // ---- weight transpose+convert, x convert, aggregation ----
    transpose_f16<<<dim3(16, 16), 256, 0, stream>>>(W_l, Wlt, 512, 512);
    transpose_f16<<<dim3(16, 16), 256, 0, stream>>>(W_r, Wrt, 512, 512);
    transpose_f16<<<dim3(8, 16), 256, 0, stream>>>(Wa, Wat, 512, 256);
    transpose_f16<<<dim3(4, 8), 256, 0, stream>>>(W1, W1t, 256, 128);
    transpose_f16<<<dim3(2, 4), 256, 0, stream>>>(W2, W2t, 128, 64);
    cvt_f16_kernel<<<(NN * DD / 8) / 256, 256, 0, stream>>>(x, x_h);
    agg_kernel<<<NN / 4, 256, 0, stream>>>(x, row_ptr, csr, agg_h);

    // ---- MLP chain (f16 MFMA) ----
    // h1 = relu(agg@W_l + x@W_r + b_l)  [8192,512]
    gemm_mfma<128, 128, 2, 4, 512><<<dim3(4, 64), 512, 0, stream>>>(
        agg_h, Wlt, x_h, Wrt, b_l, h1, NN, 512, 512, 1);
    // h2 = relu(h1@Wa + ba)             [8192,256]
    gemm_mfma<128, 64, 2, 2, 256><<<dim3(4, 64), 256, 0, stream>>>(
        h1, Wat, nullptr, nullptr, ba, h2, NN, 256, 512, 1);
    // h3 = relu(h2@W1 + b1)             [8192,128]
    gemm_mfma<64, 64, 2, 2, 256><<<dim3(2, 128), 256, 0, stream>>>(
        h2, W1t, nullptr, nullptr, b1, h3, NN, 128, 256, 1);
    // h4 = relu(h3@W2 + b2)             [8192,64]
    gemm_mfma<64, 64, 2, 2, 256><<<dim3(1, 128), 256, 0, stream>>>(
        h3, W2t, nullptr, nullptr, b2, h4, NN, 64, 128, 1);
    // y = h4@W3 + b3                     [8192,3]
    out3_kernel<<<NN / 256, 256, 0, stream>>>(h4, W3, b3, yv);

    // ---- cdist ----
    cdist_kernel<<<dim3(NN / 256, NN / 64), 256, 0, stream>>>(yv, out);
}